// Round 1
// baseline (185.699 us; speedup 1.0000x reference)
//
#include <hip/hip_runtime.h>
#include <math.h>

#define EPS 1e-8f

// ---- workspace layout (float offsets) ----
#define OFF_CW1T 0        // [128][128]  cp_w1^T
#define OFF_CW2T 16384    // [128][256]  cp_w2^T
#define OFF_CW3T 49152    // [256][20]   cp_w3^T
#define OFF_WW1T 54272    // [128][64]   w_w1^T
#define OFF_WW2T 62464    // [64][128]   w_w2^T
#define OFF_WW3T 70656    // [128][10]   w_w3^T
#define OFF_BASIS 71936   // [1024][10]  row-normalized RBF basis
#define OFF_WB   82176    // [16384][10] softmax weights
#define OFF_WM   246016   // [16384][10] weights * cp_mean
// total = 409856 floats = 1.64 MB of ws

// ---------------------------------------------------------------------------
// prep: transpose weights to WT[k][j] (contiguous-in-j for uniform scalar
// loads) and compute the basis matrix.
// ---------------------------------------------------------------------------
__global__ __launch_bounds__(256) void prep_kernel(
    const float* __restrict__ cw1, const float* __restrict__ cw2, const float* __restrict__ cw3,
    const float* __restrict__ ww1, const float* __restrict__ ww2, const float* __restrict__ ww3,
    float* __restrict__ ws)
{
  int id = blockIdx.x * 256 + threadIdx.x;
  if (id < 16384) { int k = id >> 7, j = id & 127; ws[OFF_CW1T + id] = cw1[j*128 + k]; return; }
  id -= 16384;
  if (id < 32768) { int k = id >> 8, j = id & 255; ws[OFF_CW2T + (k*256 + j)] = cw2[j*128 + k]; return; }
  id -= 32768;
  if (id < 5120)  { int k = id / 20, j = id % 20;  ws[OFF_CW3T + id] = cw3[j*256 + k]; return; }
  id -= 5120;
  if (id < 8192)  { int k = id >> 6, j = id & 63;  ws[OFF_WW1T + id] = ww1[j*128 + k]; return; }
  id -= 8192;
  if (id < 8192)  { int k = id >> 7, j = id & 127; ws[OFF_WW2T + id] = ww2[j*64  + k]; return; }
  id -= 8192;
  if (id < 1280)  { int k = id / 10, j = id % 10;  ws[OFF_WW3T + id] = ww3[j*128 + k]; return; }
  id -= 1280;
  if (id < 1024) {
    int f = id;
    float t = (float)f * (1.0f / 1023.0f);
    float v[10]; float s = 0.f;
    #pragma unroll
    for (int p = 0; p < 10; ++p) {
      float d = t - (float)p * (1.0f / 9.0f);   // centers = p/(P-1)
      float e = expf(-d * d * 50.0f);           // 2*sigma^2 = 0.02 -> *50
      v[p] = e; s += e;
    }
    float inv = 1.0f / (s + EPS);
    #pragma unroll
    for (int p = 0; p < 10; ++p) ws[OFF_BASIS + f*10 + p] = v[p] * inv;
  }
}

// ---------------------------------------------------------------------------
// dense layer helpers. One lane = one batch row; wave g owns a column slice.
// Weight addresses are wave-uniform -> scalar loads; input row comes from LDS
// with +1-pad stride so (r+k)%32 banking is conflict-free.
// ---------------------------------------------------------------------------
template<int K, int N, int CJ, bool RELU>
__device__ __forceinline__ void dense_chunk(const float* __restrict__ in_row,
                                            float* __restrict__ out_row,
                                            const float* __restrict__ WT,
                                            const float* __restrict__ B,
                                            int jbase)
{
  float acc[CJ];
  #pragma unroll
  for (int j = 0; j < CJ; ++j) acc[j] = B[jbase + j];
  #pragma unroll 4
  for (int k = 0; k < K; ++k) {
    float xv = in_row[k];
    const float* wr = WT + k*N + jbase;
    #pragma unroll
    for (int j = 0; j < CJ; ++j) acc[j] = fmaf(xv, wr[j], acc[j]);
  }
  #pragma unroll
  for (int j = 0; j < CJ; ++j) {
    float v = acc[j];
    if (RELU) v = fmaxf(v, 0.f);
    out_row[jbase + j] = v;
  }
}

// small-N layer: wave g owns columns {g, g+8, g+16} (wave-uniform predicates)
template<int K, int N, bool TANH>
__device__ __forceinline__ void dense_small(const float* __restrict__ in_row,
                                            float* __restrict__ out_row,
                                            const float* __restrict__ WT,
                                            const float* __restrict__ B,
                                            int g)
{
  constexpr int MAXC = (N + 7) / 8;
  float acc[MAXC];
  #pragma unroll
  for (int jj = 0; jj < MAXC; ++jj) { int c = g + 8*jj; acc[jj] = (c < N) ? B[c] : 0.f; }
  #pragma unroll 2
  for (int k = 0; k < K; ++k) {
    float xv = in_row[k];
    #pragma unroll
    for (int jj = 0; jj < MAXC; ++jj) {
      int c = g + 8*jj;
      if (c < N) acc[jj] = fmaf(xv, WT[k*N + c], acc[jj]);
    }
  }
  #pragma unroll
  for (int jj = 0; jj < MAXC; ++jj) {
    int c = g + 8*jj;
    if (c < N) out_row[c] = TANH ? tanhf(acc[jj]) : acc[jj];
  }
}

// ---------------------------------------------------------------------------
// fused MLPs: 64 rows/block, 512 threads (8 waves). lane=row, wave=col-slice.
// ---------------------------------------------------------------------------
__global__ __launch_bounds__(512) void mlp_kernel(
    const float* __restrict__ x,
    const float* __restrict__ cb1, const float* __restrict__ cb2, const float* __restrict__ cb3,
    const float* __restrict__ wb1, const float* __restrict__ wb2, const float* __restrict__ wb3,
    float* __restrict__ ws)
{
  __shared__ float xs[64*129];
  __shared__ float h1[64*129];
  __shared__ float h2[64*257];
  __shared__ float cp20[64*20];
  __shared__ float lg[64*12];

  const float* WT1 = ws + OFF_CW1T;
  const float* WT2 = ws + OFF_CW2T;
  const float* WT3 = ws + OFF_CW3T;
  const float* VT1 = ws + OFF_WW1T;
  const float* VT2 = ws + OFF_WW2T;
  const float* VT3 = ws + OFF_WW3T;

  const int tid = threadIdx.x;
  const int b0  = blockIdx.x * 64;
  const int r   = tid & 63;
  const int g   = __builtin_amdgcn_readfirstlane(tid >> 6);

  // stage x tile [64][128] -> LDS (padded stride 129)
  const float4* xg = (const float4*)(x + (size_t)b0 * 128);
  #pragma unroll
  for (int i = tid; i < 2048; i += 512) {
    float4 v = xg[i];
    int rr = i >> 5, kk = (i & 31) * 4;
    float* dst = xs + rr*129 + kk;
    dst[0] = v.x; dst[1] = v.y; dst[2] = v.z; dst[3] = v.w;
  }
  __syncthreads();

  // cp MLP
  dense_chunk<128,128,16,true>(xs + r*129, h1 + r*129, WT1, cb1, g*16);
  __syncthreads();
  dense_chunk<128,256,16,true>(h1 + r*129, h2 + r*257, WT2, cb2, g*32);
  dense_chunk<128,256,16,true>(h1 + r*129, h2 + r*257, WT2, cb2, g*32 + 16);
  __syncthreads();
  dense_small<256,20,true>(h2 + r*257, cp20 + r*20, WT3, cb3, g);   // tanh'd cp
  __syncthreads();

  // w MLP (reuse h1/h2 buffers)
  dense_chunk<128,64,8,true>(xs + r*129, h1 + r*129, VT1, wb1, g*8);
  __syncthreads();
  dense_chunk<64,128,16,true>(h1 + r*129, h2 + r*257, VT2, wb2, g*16);
  __syncthreads();
  dense_small<128,10,false>(h2 + r*257, lg + r*12, VT3, wb3, g);    // logits
  __syncthreads();

  // per-row softmax + cp_mean -> w, w*cp_mean (wave 0 only; tiny)
  if (tid < 64) {
    float l[10];
    float m = -1e30f;
    #pragma unroll
    for (int p = 0; p < 10; ++p) { l[p] = lg[r*12 + p]; m = fmaxf(m, l[p]); }
    float s = 0.f;
    #pragma unroll
    for (int p = 0; p < 10; ++p) { float e = expf(l[p] - m); l[p] = e; s += e; }
    float inv = 1.0f / s;
    size_t base = ((size_t)b0 + r) * 10;
    float* WB = ws + OFF_WB;
    float* WM = ws + OFF_WM;
    #pragma unroll
    for (int p = 0; p < 10; ++p) {
      float w  = l[p] * inv;
      float cm = 0.5f * (cp20[r*20 + 2*p] + cp20[r*20 + 2*p + 1]);
      WB[base + p] = w;
      WM[base + p] = w * cm;
    }
  }
}

// ---------------------------------------------------------------------------
// combine: out[b,f] = (sum_p basis[f,p]*wm[b,p]) / (sum_p basis[f,p]*w[b,p] + eps)
// 16 rows/block, 256 threads; thread owns 4 f's (basis rows in registers).
// ---------------------------------------------------------------------------
__global__ __launch_bounds__(256) void combine_kernel(const float* __restrict__ ws,
                                                      float* __restrict__ out)
{
  const float* WB  = ws + OFF_WB;
  const float* WM  = ws + OFF_WM;
  const float* BAS = ws + OFF_BASIS;
  const int tid = threadIdx.x;
  const int b0  = blockIdx.x * 16;

  __shared__ float lw[160], lwm[160];
  if (tid < 160) { lw[tid] = WB[b0*10 + tid]; lwm[tid] = WM[b0*10 + tid]; }
  __syncthreads();

  float bas[4][10];
  #pragma unroll
  for (int i = 0; i < 4; ++i) {
    int f = tid + i*256;
    #pragma unroll
    for (int p = 0; p < 10; ++p) bas[i][p] = BAS[f*10 + p];
  }

  for (int rr = 0; rr < 16; ++rr) {
    float w[10], wm[10];
    #pragma unroll
    for (int p = 0; p < 10; ++p) { w[p] = lw[rr*10 + p]; wm[p] = lwm[rr*10 + p]; }
    size_t orow = ((size_t)(b0 + rr)) * 1024 + tid;
    #pragma unroll
    for (int i = 0; i < 4; ++i) {
      float num = 0.f, den = EPS;
      #pragma unroll
      for (int p = 0; p < 10; ++p) {
        num = fmaf(bas[i][p], wm[p], num);
        den = fmaf(bas[i][p], w[p],  den);
      }
      out[orow + i*256] = num / den;
    }
  }
}

// ---------------------------------------------------------------------------
extern "C" void kernel_launch(void* const* d_in, const int* in_sizes, int n_in,
                              void* d_out, int out_size, void* d_ws, size_t ws_size,
                              hipStream_t stream)
{
  const float* x   = (const float*)d_in[0];
  const float* cw1 = (const float*)d_in[1];
  const float* cb1 = (const float*)d_in[2];
  const float* cw2 = (const float*)d_in[3];
  const float* cb2 = (const float*)d_in[4];
  const float* cw3 = (const float*)d_in[5];
  const float* cb3 = (const float*)d_in[6];
  const float* ww1 = (const float*)d_in[7];
  const float* wb1 = (const float*)d_in[8];
  const float* ww2 = (const float*)d_in[9];
  const float* wb2 = (const float*)d_in[10];
  const float* ww3 = (const float*)d_in[11];
  const float* wb3 = (const float*)d_in[12];
  float* ws  = (float*)d_ws;
  float* out = (float*)d_out;

  prep_kernel<<<285, 256, 0, stream>>>(cw1, cw2, cw3, ww1, ww2, ww3, ws);
  mlp_kernel<<<256, 512, 0, stream>>>(x, cb1, cb2, cb3, wb1, wb2, wb3, ws);
  combine_kernel<<<1024, 256, 0, stream>>>(ws, out);
}

// Round 2
// 138.116 us; speedup vs baseline: 1.3445x; 1.3445x over previous
//
#include <hip/hip_runtime.h>
#include <math.h>

#define EPS 1e-8f

// ---- workspace layout (float offsets) ----
#define OFF_CW1T 0        // [128][128]  cp_w1^T
#define OFF_CW2T 16384    // [128][256]  cp_w2^T
#define OFF_CW3T 49152    // [256][20]   cp_w3^T
#define OFF_WW1T 54272    // [128][64]   w_w1^T
#define OFF_WW2T 62464    // [64][128]   w_w2^T
#define OFF_WW3T 70656    // [128][10]   w_w3^T
#define OFF_BASIS 71936   // [1024][10]  row-normalized RBF basis
#define OFF_WB   82176    // [16384][10] softmax weights
#define OFF_WM   246016   // [16384][10] weights * cp_mean

// ---------------------------------------------------------------------------
// prep: transpose weights to WT[k][j] and compute the basis matrix.
// ---------------------------------------------------------------------------
__global__ __launch_bounds__(256) void prep_kernel(
    const float* __restrict__ cw1, const float* __restrict__ cw2, const float* __restrict__ cw3,
    const float* __restrict__ ww1, const float* __restrict__ ww2, const float* __restrict__ ww3,
    float* __restrict__ ws)
{
  int id = blockIdx.x * 256 + threadIdx.x;
  if (id < 16384) { int k = id >> 7, j = id & 127; ws[OFF_CW1T + id] = cw1[j*128 + k]; return; }
  id -= 16384;
  if (id < 32768) { int k = id >> 8, j = id & 255; ws[OFF_CW2T + (k*256 + j)] = cw2[j*128 + k]; return; }
  id -= 32768;
  if (id < 5120)  { int k = id / 20, j = id % 20;  ws[OFF_CW3T + id] = cw3[j*256 + k]; return; }
  id -= 5120;
  if (id < 8192)  { int k = id >> 6, j = id & 63;  ws[OFF_WW1T + id] = ww1[j*128 + k]; return; }
  id -= 8192;
  if (id < 8192)  { int k = id >> 7, j = id & 127; ws[OFF_WW2T + id] = ww2[j*64  + k]; return; }
  id -= 8192;
  if (id < 1280)  { int k = id / 10, j = id % 10;  ws[OFF_WW3T + id] = ww3[j*128 + k]; return; }
  id -= 1280;
  if (id < 1024) {
    int f = id;
    float t = (float)f * (1.0f / 1023.0f);
    float v[10]; float s = 0.f;
    #pragma unroll
    for (int p = 0; p < 10; ++p) {
      float d = t - (float)p * (1.0f / 9.0f);
      float e = expf(-d * d * 50.0f);
      v[p] = e; s += e;
    }
    float inv = 1.0f / (s + EPS);
    #pragma unroll
    for (int p = 0; p < 10; ++p) ws[OFF_BASIS + f*10 + p] = v[p] * inv;
  }
}

// ---------------------------------------------------------------------------
// register-tiled dense k-loop: lane owns rows {r0, r0+1} and TC columns at cb.
// A operand from LDS (broadcast within lane-quad, conflict-free w/ padded LD);
// weights streamed from global (L2-resident), float4/float2 vectorized.
// ---------------------------------------------------------------------------
template<int K, int N, int TC, int LD>
__device__ __forceinline__ void kloop2(const float* __restrict__ A, int r0, int cb,
                                       const float* __restrict__ WT,
                                       const float* __restrict__ bias,
                                       float (&a0)[TC], float (&a1)[TC])
{
  #pragma unroll
  for (int j = 0; j < TC; ++j) { float b = bias[cb + j]; a0[j] = b; a1[j] = b; }
  const float* p0 = A + r0 * LD;
  const float* wr = WT + cb;
  #pragma unroll 8
  for (int k = 0; k < K; ++k) {
    float x0 = p0[k], x1 = p0[LD + k];
    if constexpr (TC >= 4) {
      #pragma unroll
      for (int j = 0; j < TC; j += 4) {
        float4 wv = *(const float4*)(wr + (size_t)k * N + j);
        a0[j+0] = fmaf(x0, wv.x, a0[j+0]); a1[j+0] = fmaf(x1, wv.x, a1[j+0]);
        a0[j+1] = fmaf(x0, wv.y, a0[j+1]); a1[j+1] = fmaf(x1, wv.y, a1[j+1]);
        a0[j+2] = fmaf(x0, wv.z, a0[j+2]); a1[j+2] = fmaf(x1, wv.z, a1[j+2]);
        a0[j+3] = fmaf(x0, wv.w, a0[j+3]); a1[j+3] = fmaf(x1, wv.w, a1[j+3]);
      }
    } else {
      float2 wv = *(const float2*)(wr + (size_t)k * N);
      a0[0] = fmaf(x0, wv.x, a0[0]); a1[0] = fmaf(x1, wv.x, a1[0]);
      a0[1] = fmaf(x0, wv.y, a0[1]); a1[1] = fmaf(x1, wv.y, a1[1]);
    }
  }
}

// ---------------------------------------------------------------------------
// fused MLPs: 32 rows/block, 512 threads (8 waves), lane-quad = row pair,
// sub-lane + wave = column split. h2/hv2 stay in registers (L3/V3 fused).
// ---------------------------------------------------------------------------
__global__ __launch_bounds__(512, 4) void mlp_kernel(
    const float* __restrict__ x,
    const float* __restrict__ cb1, const float* __restrict__ cb2, const float* __restrict__ cb3,
    const float* __restrict__ wb1, const float* __restrict__ wb2, const float* __restrict__ wb3,
    float* __restrict__ ws)
{
  __shared__ float bufA[32 * 129];   // x tile
  __shared__ float bufB[32 * 129];   // hv1/vpbuf, then h1, then pbuf
  __shared__ float wbuf[32 * 10];    // softmax weights w[r][p]

  const float* WT1 = ws + OFF_CW1T;
  const float* WT2 = ws + OFF_CW2T;
  const float* WT3 = ws + OFF_CW3T;
  const float* VT1 = ws + OFF_WW1T;
  const float* VT2 = ws + OFF_WW2T;
  const float* VT3 = ws + OFF_WW3T;

  const int tid = threadIdx.x;
  const int l   = tid & 63;
  const int w   = tid >> 6;        // 0..7
  const int q   = l >> 2;          // 0..15
  const int sub = l & 3;           // 0..3
  const int r0  = q * 2;           // rows r0, r0+1
  const int b0  = blockIdx.x * 32;

  // ---- stage x [32][128] -> bufA (ld 129)
  {
    const float4* xg = (const float4*)(x + (size_t)b0 * 128);
    #pragma unroll
    for (int i = tid; i < 1024; i += 512) {
      float4 v = xg[i];
      int rr = i >> 5, kk = (i & 31) * 4;
      float* d = bufA + rr * 129 + kk;
      d[0] = v.x; d[1] = v.y; d[2] = v.z; d[3] = v.w;
    }
  }
  __syncthreads();

  // ================= V path =================
  float* hv1 = bufB;                       // [32][65]
  {
    float a0[2], a1[2];
    int cb = w * 8 + sub * 2;
    kloop2<128, 64, 2, 129>(bufA, r0, cb, VT1, wb1, a0, a1);
    hv1[r0 * 65 + cb]           = fmaxf(a0[0], 0.f);
    hv1[r0 * 65 + cb + 1]       = fmaxf(a0[1], 0.f);
    hv1[(r0 + 1) * 65 + cb]     = fmaxf(a1[0], 0.f);
    hv1[(r0 + 1) * 65 + cb + 1] = fmaxf(a1[1], 0.f);
  }
  __syncthreads();

  float vp0[10], vp1[10];
  {
    float a0[4], a1[4];
    int cb = w * 16 + sub * 4;
    kloop2<64, 128, 4, 65>(hv1, r0, cb, VT2, wb2, a0, a1);
    #pragma unroll
    for (int j = 0; j < 4; ++j) { a0[j] = fmaxf(a0[j], 0.f); a1[j] = fmaxf(a1[j], 0.f); }
    #pragma unroll
    for (int j = 0; j < 10; ++j) { vp0[j] = 0.f; vp1[j] = 0.f; }
    #pragma unroll
    for (int c = 0; c < 4; ++c) {
      const float* t3 = VT3 + (cb + c) * 10;
      #pragma unroll
      for (int j = 0; j < 10; j += 2) {
        float2 tv = *(const float2*)(t3 + j);
        vp0[j]   = fmaf(a0[c], tv.x, vp0[j]);   vp1[j]   = fmaf(a1[c], tv.x, vp1[j]);
        vp0[j+1] = fmaf(a0[c], tv.y, vp0[j+1]); vp1[j+1] = fmaf(a1[c], tv.y, vp1[j+1]);
      }
    }
    #pragma unroll
    for (int j = 0; j < 10; ++j) {
      vp0[j] += __shfl_xor(vp0[j], 1); vp0[j] += __shfl_xor(vp0[j], 2);
      vp1[j] += __shfl_xor(vp1[j], 1); vp1[j] += __shfl_xor(vp1[j], 2);
    }
  }
  float* vpbuf = bufB + 2080;              // [4][32][10] = 1280 floats
  if (w >= 4 && sub == 0) {
    float* d = vpbuf + (w - 4) * 320 + r0 * 10;
    #pragma unroll
    for (int j = 0; j < 10; ++j) { d[j] = vp0[j]; d[10 + j] = vp1[j]; }
  }
  __syncthreads();
  if (w < 4 && sub == 0) {
    const float* s = vpbuf + w * 320 + r0 * 10;
    #pragma unroll
    for (int j = 0; j < 10; ++j) { vp0[j] += s[j]; vp1[j] += s[10 + j]; }
  }
  __syncthreads();
  if (w >= 1 && w < 4 && sub == 0) {
    float* d = vpbuf + (w - 1) * 320 + r0 * 10;
    #pragma unroll
    for (int j = 0; j < 10; ++j) { d[j] = vp0[j]; d[10 + j] = vp1[j]; }
  }
  __syncthreads();
  if (w == 0 && sub == 0) {
    #pragma unroll
    for (int i = 0; i < 3; ++i) {
      const float* s = vpbuf + i * 320 + r0 * 10;
      #pragma unroll
      for (int j = 0; j < 10; ++j) { vp0[j] += s[j]; vp1[j] += s[10 + j]; }
    }
    float* WB = ws + OFF_WB;
    #pragma unroll
    for (int i = 0; i < 2; ++i) {
      float lgt[10];
      float m = -1e30f;
      #pragma unroll
      for (int j = 0; j < 10; ++j) {
        float v = (i == 0 ? vp0[j] : vp1[j]) + wb3[j];
        lgt[j] = v; m = fmaxf(m, v);
      }
      float s = 0.f;
      #pragma unroll
      for (int j = 0; j < 10; ++j) { float e = expf(lgt[j] - m); lgt[j] = e; s += e; }
      float inv = 1.0f / s;
      int r = r0 + i;
      #pragma unroll
      for (int j = 0; j < 10; ++j) {
        float wv = lgt[j] * inv;
        wbuf[r * 10 + j] = wv;
        WB[(size_t)(b0 + r) * 10 + j] = wv;
      }
    }
  }
  __syncthreads();

  // ================= cp path =================
  float* h1 = bufB;                        // [32][129], overwrites hv1/vpbuf
  {
    float a0[4], a1[4];
    int cb = w * 16 + sub * 4;
    kloop2<128, 128, 4, 129>(bufA, r0, cb, WT1, cb1, a0, a1);
    #pragma unroll
    for (int j = 0; j < 4; ++j) {
      h1[r0 * 129 + cb + j]       = fmaxf(a0[j], 0.f);
      h1[(r0 + 1) * 129 + cb + j] = fmaxf(a1[j], 0.f);
    }
  }
  __syncthreads();

  float cp0[20], cp1[20];
  {
    float a0[8], a1[8];
    int cb = w * 32 + sub * 8;
    kloop2<128, 256, 8, 129>(h1, r0, cb, WT2, cb2, a0, a1);
    #pragma unroll
    for (int j = 0; j < 8; ++j) { a0[j] = fmaxf(a0[j], 0.f); a1[j] = fmaxf(a1[j], 0.f); }
    #pragma unroll
    for (int j = 0; j < 20; ++j) { cp0[j] = 0.f; cp1[j] = 0.f; }
    #pragma unroll
    for (int c = 0; c < 8; ++c) {
      const float* t3 = WT3 + (cb + c) * 20;
      #pragma unroll
      for (int j = 0; j < 20; j += 4) {
        float4 tv = *(const float4*)(t3 + j);
        cp0[j]   = fmaf(a0[c], tv.x, cp0[j]);   cp1[j]   = fmaf(a1[c], tv.x, cp1[j]);
        cp0[j+1] = fmaf(a0[c], tv.y, cp0[j+1]); cp1[j+1] = fmaf(a1[c], tv.y, cp1[j+1]);
        cp0[j+2] = fmaf(a0[c], tv.z, cp0[j+2]); cp1[j+2] = fmaf(a1[c], tv.z, cp1[j+2]);
        cp0[j+3] = fmaf(a0[c], tv.w, cp0[j+3]); cp1[j+3] = fmaf(a1[c], tv.w, cp1[j+3]);
      }
    }
    #pragma unroll
    for (int j = 0; j < 20; ++j) {
      cp0[j] += __shfl_xor(cp0[j], 1); cp0[j] += __shfl_xor(cp0[j], 2);
      cp1[j] += __shfl_xor(cp1[j], 1); cp1[j] += __shfl_xor(cp1[j], 2);
    }
  }
  __syncthreads();                          // all waves done reading h1
  float* pbuf = bufB;                       // [4][32][20] = 2560 floats
  if (w >= 4 && sub == 0) {
    float* d = pbuf + (w - 4) * 640 + r0 * 20;
    #pragma unroll
    for (int j = 0; j < 20; ++j) { d[j] = cp0[j]; d[20 + j] = cp1[j]; }
  }
  __syncthreads();
  if (w < 4 && sub == 0) {
    const float* s = pbuf + w * 640 + r0 * 20;
    #pragma unroll
    for (int j = 0; j < 20; ++j) { cp0[j] += s[j]; cp1[j] += s[20 + j]; }
  }
  __syncthreads();
  if (w >= 1 && w < 4 && sub == 0) {
    float* d = pbuf + (w - 1) * 640 + r0 * 20;
    #pragma unroll
    for (int j = 0; j < 20; ++j) { d[j] = cp0[j]; d[20 + j] = cp1[j]; }
  }
  __syncthreads();
  if (w == 0 && sub == 0) {
    #pragma unroll
    for (int i = 0; i < 3; ++i) {
      const float* s = pbuf + i * 640 + r0 * 20;
      #pragma unroll
      for (int j = 0; j < 20; ++j) { cp0[j] += s[j]; cp1[j] += s[20 + j]; }
    }
    float* WM = ws + OFF_WM;
    #pragma unroll
    for (int i = 0; i < 2; ++i) {
      int r = r0 + i;
      #pragma unroll
      for (int p = 0; p < 10; ++p) {
        float v0 = (i == 0 ? cp0[2*p]   : cp1[2*p])   + cb3[2*p];
        float v1 = (i == 0 ? cp0[2*p+1] : cp1[2*p+1]) + cb3[2*p+1];
        float cm = 0.5f * (tanhf(v0) + tanhf(v1));
        WM[(size_t)(b0 + r) * 10 + p] = wbuf[r * 10 + p] * cm;
      }
    }
  }
}

// ---------------------------------------------------------------------------
// combine: out[b,f] = (sum_p basis[f,p]*wm[b,p]) / (sum_p basis[f,p]*w[b,p]+eps)
// 16 rows/block, 256 threads; thread owns 4 consecutive f's -> float4 stores.
// ---------------------------------------------------------------------------
__global__ __launch_bounds__(256) void combine_kernel(const float* __restrict__ ws,
                                                      float* __restrict__ out)
{
  const float* WB  = ws + OFF_WB;
  const float* WM  = ws + OFF_WM;
  const float* BAS = ws + OFF_BASIS;
  const int tid = threadIdx.x;
  const int b0  = blockIdx.x * 16;

  __shared__ float lw[160], lwm[160];
  if (tid < 160) { lw[tid] = WB[b0 * 10 + tid]; lwm[tid] = WM[b0 * 10 + tid]; }
  __syncthreads();

  const int f0 = tid * 4;
  float bas[4][10];
  #pragma unroll
  for (int i = 0; i < 4; ++i) {
    const float2* bp = (const float2*)(BAS + (f0 + i) * 10);
    #pragma unroll
    for (int p = 0; p < 5; ++p) { float2 v = bp[p]; bas[i][2*p] = v.x; bas[i][2*p+1] = v.y; }
  }

  for (int rr = 0; rr < 16; ++rr) {
    float wv[10], wm[10];
    #pragma unroll
    for (int p = 0; p < 10; ++p) { wv[p] = lw[rr*10 + p]; wm[p] = lwm[rr*10 + p]; }
    float o[4];
    #pragma unroll
    for (int i = 0; i < 4; ++i) {
      float num = 0.f, den = EPS;
      #pragma unroll
      for (int p = 0; p < 10; ++p) {
        num = fmaf(bas[i][p], wm[p], num);
        den = fmaf(bas[i][p], wv[p], den);
      }
      o[i] = num / den;
    }
    float4 ov = make_float4(o[0], o[1], o[2], o[3]);
    *(float4*)(out + (size_t)(b0 + rr) * 1024 + f0) = ov;
  }
}

// ---------------------------------------------------------------------------
extern "C" void kernel_launch(void* const* d_in, const int* in_sizes, int n_in,
                              void* d_out, int out_size, void* d_ws, size_t ws_size,
                              hipStream_t stream)
{
  const float* x   = (const float*)d_in[0];
  const float* cw1 = (const float*)d_in[1];
  const float* cb1 = (const float*)d_in[2];
  const float* cw2 = (const float*)d_in[3];
  const float* cb2 = (const float*)d_in[4];
  const float* cw3 = (const float*)d_in[5];
  const float* cb3 = (const float*)d_in[6];
  const float* ww1 = (const float*)d_in[7];
  const float* wb1 = (const float*)d_in[8];
  const float* ww2 = (const float*)d_in[9];
  const float* wb2 = (const float*)d_in[10];
  const float* ww3 = (const float*)d_in[11];
  const float* wb3 = (const float*)d_in[12];
  float* ws  = (float*)d_ws;
  float* out = (float*)d_out;

  prep_kernel<<<285, 256, 0, stream>>>(cw1, cw2, cw3, ww1, ww2, ww3, ws);
  mlp_kernel<<<512, 512, 0, stream>>>(x, cb1, cb2, cb3, wb1, wb2, wb3, ws);
  combine_kernel<<<1024, 256, 0, stream>>>(ws, out);
}

// Round 4
// 113.425 us; speedup vs baseline: 1.6372x; 1.2177x over previous
//
#include <hip/hip_runtime.h>
#include <math.h>

#define EPS 1e-8f

// ---- ws layout (float offsets): weights transposed to [k][j] + basis ----
#define OFF_CW1T 0        // [128][128]
#define OFF_CW2T 16384    // [128][256]
#define OFF_CW3T 49152    // [256][20]
#define OFF_WW1T 54272    // [128][64]
#define OFF_WW2T 62464    // [64][128]
#define OFF_WW3T 70656    // [128][10]
#define OFF_BASIS 71936   // [1024][10]

// ---------------------------------------------------------------------------
__global__ __launch_bounds__(256) void prep_kernel(
    const float* __restrict__ cw1, const float* __restrict__ cw2, const float* __restrict__ cw3,
    const float* __restrict__ ww1, const float* __restrict__ ww2, const float* __restrict__ ww3,
    float* __restrict__ ws)
{
  int id = blockIdx.x * 256 + threadIdx.x;
  if (id < 16384) { int k = id >> 7, j = id & 127; ws[OFF_CW1T + id] = cw1[j*128 + k]; return; }
  id -= 16384;
  if (id < 32768) { int k = id >> 8, j = id & 255; ws[OFF_CW2T + (k*256 + j)] = cw2[j*128 + k]; return; }
  id -= 32768;
  if (id < 5120)  { int k = id / 20, j = id % 20;  ws[OFF_CW3T + id] = cw3[j*256 + k]; return; }
  id -= 5120;
  if (id < 8192)  { int k = id >> 6, j = id & 63;  ws[OFF_WW1T + id] = ww1[j*128 + k]; return; }
  id -= 8192;
  if (id < 8192)  { int k = id >> 7, j = id & 127; ws[OFF_WW2T + id] = ww2[j*64  + k]; return; }
  id -= 8192;
  if (id < 1280)  { int k = id / 10, j = id % 10;  ws[OFF_WW3T + id] = ww3[j*128 + k]; return; }
  id -= 1280;
  if (id < 1024) {
    int f = id;
    float t = (float)f * (1.0f / 1023.0f);
    float v[10]; float s = 0.f;
    #pragma unroll
    for (int p = 0; p < 10; ++p) {
      float d = t - (float)p * (1.0f / 9.0f);
      float e = expf(-d * d * 50.0f);
      v[p] = e; s += e;
    }
    float inv = 1.0f / (s + EPS);
    #pragma unroll
    for (int p = 0; p < 10; ++p) ws[OFF_BASIS + f*10 + p] = v[p] * inv;
  }
}

// ---------------------------------------------------------------------------
// Fully fused: MLPs + softmax + cp_mean + basis combine + output write.
// 64 rows/block (lane = row), 16 waves (wave = wave-uniform column slice).
// LDS: xs[64*128] (x -> hv1+vbuf), hb[64*128] (h1 -> cpbuf). Rotate swizzle
// (k+l)&127 keeps ds_read_b32 conflict-free at stride 128 (2-way = free).
// ---------------------------------------------------------------------------
__global__ __launch_bounds__(1024, 4) void fused_kernel(
    const float* __restrict__ x,
    const float* __restrict__ cb1, const float* __restrict__ cb2, const float* __restrict__ cb3,
    const float* __restrict__ wb1, const float* __restrict__ wb2, const float* __restrict__ wb3,
    const float* __restrict__ ws, float* __restrict__ out)
{
  __shared__ float xs[8192];   // x tile; later hv1 [64*64] + vbuf [640] @4096
  __shared__ float hb[8192];   // h1 tile; later cpbuf [64*20] = 1280 floats

  const int tid = threadIdx.x;
  const int l   = tid & 63;                                   // lane = row
  const int w   = __builtin_amdgcn_readfirstlane(tid >> 6);   // 0..15
  const int b0  = blockIdx.x * 64;

  const float* CW1T = ws + OFF_CW1T;
  const float* CW2T = ws + OFF_CW2T;
  const float* CW3T = ws + OFF_CW3T;
  const float* WW1T = ws + OFF_WW1T;
  const float* WW2T = ws + OFF_WW2T;
  const float* WW3T = ws + OFF_WW3T;

  // ---- P0: stage x [64][128] -> xs (rotate-swizzled rows)
  {
    const float4* xg = (const float4*)(x + (size_t)b0 * 128);
    #pragma unroll
    for (int i = tid; i < 2048; i += 1024) {
      float4 v = xg[i];
      int rr = i >> 5, kk = (i & 31) << 2;
      float* row = xs + rr * 128;
      row[(kk + 0 + rr) & 127] = v.x;
      row[(kk + 1 + rr) & 127] = v.y;
      row[(kk + 2 + rr) & 127] = v.z;
      row[(kk + 3 + rr) & 127] = v.w;
    }
  }
  __syncthreads();   // B1

  // ---- P1: L1 (cp, cols 8w..8w+8) + V1 (w, cols 4w..4w+4), K=128, fused
  float accL[8], accV[4];
  {
    #pragma unroll
    for (int j = 0; j < 8; ++j) accL[j] = cb1[8*w + j];
    #pragma unroll
    for (int j = 0; j < 4; ++j) accV[j] = wb1[4*w + j];
    const float* w1 = CW1T + 8*w;
    const float* v1 = WW1T + 4*w;
    const float* xrow = xs + l * 128;
    #pragma unroll 4
    for (int k = 0; k < 128; ++k) {
      float xv = xrow[(k + l) & 127];
      float4 a = *(const float4*)(w1 + k*128);
      float4 b = *(const float4*)(w1 + k*128 + 4);
      float4 c = *(const float4*)(v1 + k*64);
      accL[0] = fmaf(xv, a.x, accL[0]);
      accL[1] = fmaf(xv, a.y, accL[1]);
      accL[2] = fmaf(xv, a.z, accL[2]);
      accL[3] = fmaf(xv, a.w, accL[3]);
      accL[4] = fmaf(xv, b.x, accL[4]);
      accL[5] = fmaf(xv, b.y, accL[5]);
      accL[6] = fmaf(xv, b.z, accL[6]);
      accL[7] = fmaf(xv, b.w, accL[7]);
      accV[0] = fmaf(xv, c.x, accV[0]);
      accV[1] = fmaf(xv, c.y, accV[1]);
      accV[2] = fmaf(xv, c.z, accV[2]);
      accV[3] = fmaf(xv, c.w, accV[3]);
    }
  }
  // write h1 (swizzled, scalar stores)
  {
    float* hrow = hb + l * 128;
    #pragma unroll
    for (int j = 0; j < 8; ++j) hrow[(8*w + j + l) & 127] = fmaxf(accL[j], 0.f);
  }
  __syncthreads();   // B2: x dead, h1 ready

  // ---- P2: hv1 -> xs[0..4096) (stride 64, swizzled); zero vbuf @ xs+4096
  {
    float* hvrow = xs + l * 64;
    #pragma unroll
    for (int j = 0; j < 4; ++j) hvrow[(4*w + j + l) & 63] = fmaxf(accV[j], 0.f);
  }
  if (tid < 640) xs[4096 + tid] = 0.f;
  __syncthreads();   // B3

  // ---- P3: V2 (cols 8w..8w+8, K=64) + fused V3 -> logit partials
  {
    float a2[8];
    #pragma unroll
    for (int j = 0; j < 8; ++j) a2[j] = wb2[8*w + j];
    const float* v2 = WW2T + 8*w;
    const float* hvrow = xs + l * 64;
    #pragma unroll 4
    for (int k = 0; k < 64; ++k) {
      float hv = hvrow[(k + l) & 63];
      float4 a = *(const float4*)(v2 + k*128);
      float4 b = *(const float4*)(v2 + k*128 + 4);
      a2[0] = fmaf(hv, a.x, a2[0]);
      a2[1] = fmaf(hv, a.y, a2[1]);
      a2[2] = fmaf(hv, a.z, a2[2]);
      a2[3] = fmaf(hv, a.w, a2[3]);
      a2[4] = fmaf(hv, b.x, a2[4]);
      a2[5] = fmaf(hv, b.y, a2[5]);
      a2[6] = fmaf(hv, b.z, a2[6]);
      a2[7] = fmaf(hv, b.w, a2[7]);
    }
    float vp[10];
    #pragma unroll
    for (int j = 0; j < 10; ++j) vp[j] = 0.f;
    #pragma unroll
    for (int c = 0; c < 8; ++c) {
      float h = fmaxf(a2[c], 0.f);
      const float* t = WW3T + (8*w + c) * 10;
      #pragma unroll
      for (int j = 0; j < 10; j += 2) {
        float2 tv = *(const float2*)(t + j);
        vp[j]   = fmaf(h, tv.x, vp[j]);
        vp[j+1] = fmaf(h, tv.y, vp[j+1]);
      }
    }
    float* vbuf = xs + 4096;
    #pragma unroll
    for (int j = 0; j < 10; ++j) atomicAdd(vbuf + l*10 + j, vp[j]);
  }
  __syncthreads();   // B4

  // ---- P4: softmax (wave 0; in-place in vbuf). Other waves proceed to L2.
  if (tid < 64) {
    float* vbuf = xs + 4096;
    float lg[10]; float m = -1e30f;
    #pragma unroll
    for (int j = 0; j < 10; ++j) { lg[j] = vbuf[l*10 + j] + wb3[j]; m = fmaxf(m, lg[j]); }
    float s = 0.f;
    #pragma unroll
    for (int j = 0; j < 10; ++j) { float e = expf(lg[j] - m); lg[j] = e; s += e; }
    float inv = __builtin_amdgcn_rcpf(s);
    #pragma unroll
    for (int j = 0; j < 10; ++j) vbuf[l*10 + j] = lg[j] * inv;
  }

  // ---- P5: L2 (cols 16w..16w+16, K=128) + fused L3 -> cp partials (regs)
  float cp[20];
  {
    float a3[16];
    #pragma unroll
    for (int j = 0; j < 16; ++j) a3[j] = cb2[16*w + j];
    const float* w2 = CW2T + 16*w;
    const float* hrow = hb + l * 128;
    #pragma unroll 2
    for (int k = 0; k < 128; ++k) {
      float hv = hrow[(k + l) & 127];
      float4 a = *(const float4*)(w2 + k*256);
      float4 b = *(const float4*)(w2 + k*256 + 4);
      float4 c = *(const float4*)(w2 + k*256 + 8);
      float4 d = *(const float4*)(w2 + k*256 + 12);
      a3[0]  = fmaf(hv, a.x, a3[0]);
      a3[1]  = fmaf(hv, a.y, a3[1]);
      a3[2]  = fmaf(hv, a.z, a3[2]);
      a3[3]  = fmaf(hv, a.w, a3[3]);
      a3[4]  = fmaf(hv, b.x, a3[4]);
      a3[5]  = fmaf(hv, b.y, a3[5]);
      a3[6]  = fmaf(hv, b.z, a3[6]);
      a3[7]  = fmaf(hv, b.w, a3[7]);
      a3[8]  = fmaf(hv, c.x, a3[8]);
      a3[9]  = fmaf(hv, c.y, a3[9]);
      a3[10] = fmaf(hv, c.z, a3[10]);
      a3[11] = fmaf(hv, c.w, a3[11]);
      a3[12] = fmaf(hv, d.x, a3[12]);
      a3[13] = fmaf(hv, d.y, a3[13]);
      a3[14] = fmaf(hv, d.z, a3[14]);
      a3[15] = fmaf(hv, d.w, a3[15]);
    }
    #pragma unroll
    for (int j = 0; j < 20; ++j) cp[j] = 0.f;
    #pragma unroll
    for (int c = 0; c < 16; ++c) {
      float h = fmaxf(a3[c], 0.f);
      const float* t = CW3T + (16*w + c) * 20;
      #pragma unroll
      for (int j = 0; j < 20; j += 4) {
        float4 tv = *(const float4*)(t + j);
        cp[j]   = fmaf(h, tv.x, cp[j]);
        cp[j+1] = fmaf(h, tv.y, cp[j+1]);
        cp[j+2] = fmaf(h, tv.z, cp[j+2]);
        cp[j+3] = fmaf(h, tv.w, cp[j+3]);
      }
    }
  }
  __syncthreads();   // B5: all h1 reads done
  // zero cpbuf [64][20] = 1280 floats (grid-stride: block has only 1024 thr!)
  for (int i = tid; i < 1280; i += 1024) hb[i] = 0.f;
  __syncthreads();   // B6
  {
    #pragma unroll
    for (int j = 0; j < 20; ++j) atomicAdd(hb + l*20 + j, cp[j]);
  }
  __syncthreads();   // B7

  // ---- P8: wm = w * cp_mean (wave 0; wm into cpbuf[r][0..10))
  if (tid < 64) {
    const float* vbuf = xs + 4096;
    #pragma unroll
    for (int p = 0; p < 10; ++p) {
      float s0 = hb[l*20 + 2*p]     + cb3[2*p];
      float s1 = hb[l*20 + 2*p + 1] + cb3[2*p + 1];
      float cm = 0.5f * (tanhf(s0) + tanhf(s1));
      hb[l*20 + p] = vbuf[l*10 + p] * cm;
    }
  }
  __syncthreads();   // B8

  // ---- P9: combine + output. thread = 2 f-cols x 32 rows.
  {
    const float* vbuf = xs + 4096;     // w  [64][10]
    const float* cpb  = hb;            // wm [64][20] (first 10 valid)
    const float* BAS  = ws + OFF_BASIS;
    const int fpair = tid & 511;
    const int rbase = (tid >> 9) * 32;
    const int f0 = fpair * 2;

    float bas[20];
    {
      const float4* bp = (const float4*)(BAS + f0 * 10);
      #pragma unroll
      for (int i = 0; i < 5; ++i) {
        float4 v = bp[i];
        bas[4*i+0] = v.x; bas[4*i+1] = v.y; bas[4*i+2] = v.z; bas[4*i+3] = v.w;
      }
    }
    for (int r = 0; r < 32; ++r) {
      int rr = rbase + r;
      float wv[10], wm[10];
      #pragma unroll
      for (int p = 0; p < 10; p += 2) {
        float2 a = *(const float2*)(vbuf + rr*10 + p);
        wv[p] = a.x; wv[p+1] = a.y;
        float2 b = *(const float2*)(cpb + rr*20 + p);
        wm[p] = b.x; wm[p+1] = b.y;
      }
      float n0 = 0.f, d0 = EPS, n1 = 0.f, d1 = EPS;
      #pragma unroll
      for (int p = 0; p < 10; ++p) {
        n0 = fmaf(bas[p],      wm[p], n0);
        d0 = fmaf(bas[p],      wv[p], d0);
        n1 = fmaf(bas[10 + p], wm[p], n1);
        d1 = fmaf(bas[10 + p], wv[p], d1);
      }
      float2 o;
      o.x = n0 * __builtin_amdgcn_rcpf(d0);
      o.y = n1 * __builtin_amdgcn_rcpf(d1);
      *(float2*)(out + (size_t)(b0 + rr) * 1024 + f0) = o;
    }
  }
}

// ---------------------------------------------------------------------------
extern "C" void kernel_launch(void* const* d_in, const int* in_sizes, int n_in,
                              void* d_out, int out_size, void* d_ws, size_t ws_size,
                              hipStream_t stream)
{
  const float* x   = (const float*)d_in[0];
  const float* cw1 = (const float*)d_in[1];
  const float* cb1 = (const float*)d_in[2];
  const float* cw2 = (const float*)d_in[3];
  const float* cb2 = (const float*)d_in[4];
  const float* cw3 = (const float*)d_in[5];
  const float* cb3 = (const float*)d_in[6];
  const float* ww1 = (const float*)d_in[7];
  const float* wb1 = (const float*)d_in[8];
  const float* ww2 = (const float*)d_in[9];
  const float* wb2 = (const float*)d_in[10];
  const float* ww3 = (const float*)d_in[11];
  const float* wb3 = (const float*)d_in[12];
  float* ws  = (float*)d_ws;
  float* out = (float*)d_out;

  prep_kernel<<<285, 256, 0, stream>>>(cw1, cw2, cw3, ww1, ww2, ww3, ws);
  fused_kernel<<<256, 1024, 0, stream>>>(x, cb1, cb2, cb3, wb1, wb2, wb3, ws, out);
}